// Round 1
// baseline (100.471 us; speedup 1.0000x reference)
//
#include <hip/hip_runtime.h>
#include <math.h>

#define M_GAUSS 1024
#define N_RAYS  32768

__device__ __forceinline__ float fexp2(float x) {
#if __has_builtin(__builtin_amdgcn_exp2f)
    return __builtin_amdgcn_exp2f(x);
#else
    return exp2f(x);
#endif
}

// ---------------------------------------------------------------------------
// Prep: invert each 4x4 SPD covariance (fp64 adjugate), pack per-gaussian
// coefficients so the hot loop is a 15-term dot product:
//   s = k*quad = w14 + sum(diag*q) + sum(offdiag*qpair) + sum(lin*p)
//   pdf = label * exp2(s),  k = -0.5*log2(e)
// W layout per gaussian (16 floats):
//   [0..3]  k*B00, k*B11, k*B22, k*B33
//   [4..9]  2k*B01, 2k*B02, 2k*B03, 2k*B12, 2k*B13, 2k*B23
//   [10..13] -2k*(B·mu)[0..3]
//   [14]    k*(mu^T B mu)
//   [15]    label
// ---------------------------------------------------------------------------
__global__ __launch_bounds__(256) void prep_kernel(
    const float* __restrict__ means,   // [M,4]
    const float* __restrict__ covs,    // [M,4,4]
    const float* __restrict__ labels,  // [M]
    float* __restrict__ W)             // [M,16]
{
    int m = blockIdx.x * blockDim.x + threadIdx.x;
    if (m >= M_GAUSS) return;
    const float* C = covs + 16 * m;
    double a00=C[0],  a01=C[1],  a02=C[2],  a03=C[3];
    double a10=C[4],  a11=C[5],  a12=C[6],  a13=C[7];
    double a20=C[8],  a21=C[9],  a22=C[10], a23=C[11];
    double a30=C[12], a31=C[13], a32=C[14], a33=C[15];

    double s0=a00*a11-a01*a10, s1=a00*a12-a02*a10, s2=a00*a13-a03*a10;
    double s3=a01*a12-a02*a11, s4=a01*a13-a03*a11, s5=a02*a13-a03*a12;
    double c5=a22*a33-a23*a32, c4=a21*a33-a23*a31, c3=a21*a32-a22*a31;
    double c2=a20*a33-a23*a30, c1=a20*a32-a22*a30, c0=a20*a31-a21*a30;
    double det = s0*c5 - s1*c4 + s2*c3 + s3*c2 - s4*c1 + s5*c0;
    double id = 1.0 / det;

    double b00=( a11*c5 - a12*c4 + a13*c3)*id;
    double b01=(-a01*c5 + a02*c4 - a03*c3)*id;
    double b10=(-a10*c5 + a12*c2 - a13*c1)*id;
    double b11=( a00*c5 - a02*c2 + a03*c1)*id;
    double b20=( a10*c4 - a11*c2 + a13*c0)*id;
    double b21=(-a00*c4 + a01*c2 - a03*c0)*id;
    double b30=(-a10*c3 + a11*c1 - a12*c0)*id;
    double b31=( a00*c3 - a01*c1 + a02*c0)*id;
    double b02=( a31*s5 - a32*s4 + a33*s3)*id;
    double b03=(-a21*s5 + a22*s4 - a23*s3)*id;
    double b12=(-a30*s5 + a32*s2 - a33*s1)*id;
    double b13=( a20*s5 - a22*s2 + a23*s1)*id;
    double b22=( a30*s4 - a31*s2 + a33*s0)*id;
    double b23=(-a20*s4 + a21*s2 - a23*s0)*id;
    double b32=(-a30*s3 + a31*s1 - a32*s0)*id;
    double b33=( a20*s3 - a21*s1 + a22*s0)*id;

    // symmetrize (B is inverse of SPD, symmetric up to rounding)
    double m01=0.5*(b01+b10), m02=0.5*(b02+b20), m03=0.5*(b03+b30);
    double m12=0.5*(b12+b21), m13=0.5*(b13+b31), m23=0.5*(b23+b32);

    const float* mu = means + 4*m;
    double u0=mu[0], u1=mu[1], u2=mu[2], u3=mu[3];
    double v0 = b00*u0 + m01*u1 + m02*u2 + m03*u3;
    double v1 = m01*u0 + b11*u1 + m12*u2 + m13*u3;
    double v2 = m02*u0 + m12*u1 + b22*u2 + m23*u3;
    double v3 = m03*u0 + m13*u1 + m23*u2 + b33*u3;
    double cc = u0*v0 + u1*v1 + u2*v2 + u3*v3;

    const double k = -0.72134752044448170368;   // -0.5 * log2(e)
    float* w = W + 16*m;
    w[0]=(float)(k*b00);  w[1]=(float)(k*b11);  w[2]=(float)(k*b22);  w[3]=(float)(k*b33);
    w[4]=(float)(2.0*k*m01); w[5]=(float)(2.0*k*m02); w[6]=(float)(2.0*k*m03);
    w[7]=(float)(2.0*k*m12); w[8]=(float)(2.0*k*m13); w[9]=(float)(2.0*k*m23);
    w[10]=(float)(-2.0*k*v0); w[11]=(float)(-2.0*k*v1);
    w[12]=(float)(-2.0*k*v2); w[13]=(float)(-2.0*k*v3);
    w[14]=(float)(k*cc);
    w[15]=labels[m];
}

// ---------------------------------------------------------------------------
// Main: block = 256 threads = 4 waves; each block owns 64 rays (lane = ray),
// each wave covers a 256-gaussian slice. Gaussian data is wave-uniform:
// readfirstlane on the index lets the compiler use scalar loads / SGPR
// operands. LDS reduction across the 4 waves, then sigmoid.
// ---------------------------------------------------------------------------
__global__ __launch_bounds__(256) void decoder_kernel(
    const float2* __restrict__ org,   // [N] (origins as float2)
    const float2* __restrict__ dir,   // [N]
    const float* __restrict__ W,      // [M,16]
    float* __restrict__ out)          // [N]
{
    const int lane = threadIdx.x & 63;
    const int wave = threadIdx.x >> 6;
    const int ray  = (blockIdx.x << 6) + lane;

    const float2 o = org[ray];
    const float2 d = dir[ray];
    const float p0=o.x, p1=o.y, p2=d.x, p3=d.y;
    // monomial features
    const float q0=p0*p0, q1=p1*p1, q2=p2*p2, q3=p3*p3;
    const float q4=p0*p1, q5=p0*p2, q6=p0*p3;
    const float q7=p1*p2, q8=p1*p3, q9=p2*p3;

    float acc = 0.0f;
    const int m0 = wave << 8;   // 256 gaussians per wave

    #pragma unroll 4
    for (int m = 0; m < 256; ++m) {
        const int mm = __builtin_amdgcn_readfirstlane(m0 + m);
        const float4* w4 = reinterpret_cast<const float4*>(W + (mm << 4));
        const float4 wa = w4[0];   // diag
        const float4 wb = w4[1];   // offdiag 01,02,03,12
        const float4 wc = w4[2];   // offdiag 13,23 | lin0,lin1
        const float4 wd = w4[3];   // lin2,lin3 | const | label

        // two chains to halve dependent-FMA latency
        float sA = wd.z;
        sA = fmaf(wa.x, q0, sA);
        sA = fmaf(wa.z, q2, sA);
        sA = fmaf(wb.x, q4, sA);
        sA = fmaf(wb.z, q6, sA);
        sA = fmaf(wc.x, q8, sA);
        sA = fmaf(wc.z, p0, sA);
        sA = fmaf(wd.x, p2, sA);
        float sB = wa.y * q1;
        sB = fmaf(wa.w, q3, sB);
        sB = fmaf(wb.y, q5, sB);
        sB = fmaf(wb.w, q7, sB);
        sB = fmaf(wc.y, q9, sB);
        sB = fmaf(wc.w, p1, sB);
        sB = fmaf(wd.y, p3, sB);

        acc = fmaf(wd.w, fexp2(sA + sB), acc);
    }

    __shared__ float partial[4][64];
    partial[wave][lane] = acc;
    __syncthreads();

    if (wave == 0) {
        const float t = partial[0][lane] + partial[1][lane]
                      + partial[2][lane] + partial[3][lane];
        // sigmoid(t) = 1 / (1 + exp2(-t*log2e))
        const float e = fexp2(-t * 1.4426950408889634f);
        out[ray] = 1.0f / (1.0f + e);
    }
}

extern "C" void kernel_launch(void* const* d_in, const int* in_sizes, int n_in,
                              void* d_out, int out_size, void* d_ws, size_t ws_size,
                              hipStream_t stream) {
    const float* origins    = (const float*)d_in[0];  // [N,2]
    const float* directions = (const float*)d_in[1];  // [N,2]
    const float* means      = (const float*)d_in[2];  // [M,4]
    const float* covs       = (const float*)d_in[3];  // [M,4,4]
    const float* labels     = (const float*)d_in[4];  // [M]
    float* out = (float*)d_out;
    float* W   = (float*)d_ws;                        // [M,16] = 64 KB

    prep_kernel<<<dim3(M_GAUSS / 256), dim3(256), 0, stream>>>(means, covs, labels, W);
    decoder_kernel<<<dim3(N_RAYS / 64), dim3(256), 0, stream>>>(
        (const float2*)origins, (const float2*)directions, W, out);
}

// Round 2
// 80.760 us; speedup vs baseline: 1.2441x; 1.2441x over previous
//
#include <hip/hip_runtime.h>
#include <math.h>

#define M_GAUSS 1024
#define N_RAYS  32768

typedef float v2f __attribute__((ext_vector_type(2)));

__device__ __forceinline__ float fexp2(float x) {
#if __has_builtin(__builtin_amdgcn_exp2f)
    return __builtin_amdgcn_exp2f(x);
#else
    return exp2f(x);
#endif
}

__device__ __forceinline__ v2f fma2(v2f a, v2f b, v2f c) {
#if __has_builtin(__builtin_elementwise_fma)
    return __builtin_elementwise_fma(a, b, c);
#else
    v2f r; r.x = fmaf(a.x, b.x, c.x); r.y = fmaf(a.y, b.y, c.y); return r;
#endif
}

__device__ __forceinline__ v2f mkv2(float x, float y) { v2f r; r.x = x; r.y = y; return r; }

// ---------------------------------------------------------------------------
// Fused kernel. Block = 1024 threads = 16 waves, handles 64 rays (lane=ray).
// Phase 1 (prep): thread t inverts covariance t (fp32 adjugate) and packs a
//   16-float coefficient row into LDS:
//     pairs (0,1)..(12,13) dot the feature pairs f0..f6, [14]=const, [15]=label
//     with k = -0.5*log2(e) folded in so pdf = label * exp2(dot + const).
// Phase 2 (main): wave w sweeps gaussians [w*64, w*64+64) from LDS
//   (wave-uniform address -> ds_read_b128 broadcast, conflict-free),
//   7 packed-fp32 FMA pairs per gaussian + exp2 + accumulate.
// Phase 3: 16-wave LDS reduction (reuses the W table region), sigmoid, store.
// LDS = exactly 64 KB -> 2 blocks/CU -> 32 waves/CU.
// ---------------------------------------------------------------------------
__global__ __launch_bounds__(1024, 8) void decoder_fused(
    const float2* __restrict__ org,   // [N]
    const float2* __restrict__ dir,   // [N]
    const float*  __restrict__ means, // [M,4]
    const float*  __restrict__ covs,  // [M,4,4]
    const float*  __restrict__ labels,// [M]
    float*        __restrict__ out)   // [N]
{
    __shared__ float smemW[M_GAUSS * 16];   // 65536 B; reused for reduction

    const int tid  = threadIdx.x;
    const int lane = tid & 63;
    const int wave = tid >> 6;
    const int ray  = (blockIdx.x << 6) + lane;

    // ---------------- Phase 1: per-gaussian coefficient prep (fp32) --------
    {
        const int g = tid;                      // one gaussian per thread
        const float4* C4 = reinterpret_cast<const float4*>(covs + 16 * g);
        const float4 r0 = C4[0], r1 = C4[1], r2 = C4[2], r3 = C4[3];
        const float a00=r0.x, a01=r0.y, a02=r0.z, a03=r0.w;
        const float a10=r1.x, a11=r1.y, a12=r1.z, a13=r1.w;
        const float a20=r2.x, a21=r2.y, a22=r2.z, a23=r2.w;
        const float a30=r3.x, a31=r3.y, a32=r3.z, a33=r3.w;

        const float s0=a00*a11-a01*a10, s1=a00*a12-a02*a10, s2=a00*a13-a03*a10;
        const float s3=a01*a12-a02*a11, s4=a01*a13-a03*a11, s5=a02*a13-a03*a12;
        const float c5=a22*a33-a23*a32, c4=a21*a33-a23*a31, c3=a21*a32-a22*a31;
        const float c2=a20*a33-a23*a30, c1=a20*a32-a22*a30, c0=a20*a31-a21*a30;
        const float det = s0*c5 - s1*c4 + s2*c3 + s3*c2 - s4*c1 + s5*c0;
        const float id  = 1.0f / det;           // det >= 1 for SPD AA^T+I

        const float b00=( a11*c5 - a12*c4 + a13*c3)*id;
        const float b01=(-a01*c5 + a02*c4 - a03*c3)*id;
        const float b10=(-a10*c5 + a12*c2 - a13*c1)*id;
        const float b11=( a00*c5 - a02*c2 + a03*c1)*id;
        const float b20=( a10*c4 - a11*c2 + a13*c0)*id;
        const float b21=(-a00*c4 + a01*c2 - a03*c0)*id;
        const float b30=(-a10*c3 + a11*c1 - a12*c0)*id;
        const float b31=( a00*c3 - a01*c1 + a02*c0)*id;
        const float b02=( a31*s5 - a32*s4 + a33*s3)*id;
        const float b03=(-a21*s5 + a22*s4 - a23*s3)*id;
        const float b12=(-a30*s5 + a32*s2 - a33*s1)*id;
        const float b13=( a20*s5 - a22*s2 + a23*s1)*id;
        const float b22=( a30*s4 - a31*s2 + a33*s0)*id;
        const float b23=(-a20*s4 + a21*s2 - a23*s0)*id;
        const float b32=(-a30*s3 + a31*s1 - a32*s0)*id;
        const float b33=( a20*s3 - a21*s1 + a22*s0)*id;

        const float m01=0.5f*(b01+b10), m02=0.5f*(b02+b20), m03=0.5f*(b03+b30);
        const float m12=0.5f*(b12+b21), m13=0.5f*(b13+b31), m23=0.5f*(b23+b32);

        const float4 mu = reinterpret_cast<const float4*>(means)[g];
        const float u0=mu.x, u1=mu.y, u2=mu.z, u3=mu.w;
        const float v0 = b00*u0 + m01*u1 + m02*u2 + m03*u3;
        const float v1 = m01*u0 + b11*u1 + m12*u2 + m13*u3;
        const float v2 = m02*u0 + m12*u1 + b22*u2 + m23*u3;
        const float v3 = m03*u0 + m13*u1 + m23*u2 + b33*u3;
        const float cc = u0*v0 + u1*v1 + u2*v2 + u3*v3;

        const float k  = -0.72134752044448170368f;   // -0.5 * log2(e)
        const float k2 = 2.0f * k;
        float* w = smemW + 16 * g;
        w[0]  = k*b00;   w[1]  = k*b11;   w[2]  = k*b22;   w[3]  = k*b33;
        w[4]  = k2*m01;  w[5]  = k2*m02;  w[6]  = k2*m03;  w[7]  = k2*m12;
        w[8]  = k2*m13;  w[9]  = k2*m23;  w[10] = -k2*v0;  w[11] = -k2*v1;
        w[12] = -k2*v2;  w[13] = -k2*v3;  w[14] = k*cc;    w[15] = labels[g];
    }
    __syncthreads();

    // ---------------- Phase 2: main sweep -----------------------------------
    const float2 o = org[ray];
    const float2 d = dir[ray];
    const float p0=o.x, p1=o.y, p2=d.x, p3=d.y;

    const v2f f0 = mkv2(p0*p0, p1*p1);
    const v2f f1 = mkv2(p2*p2, p3*p3);
    const v2f f2 = mkv2(p0*p1, p0*p2);
    const v2f f3 = mkv2(p0*p3, p1*p2);
    const v2f f4 = mkv2(p1*p3, p2*p3);
    const v2f f5 = mkv2(p0, p1);
    const v2f f6 = mkv2(p2, p3);

    float acc = 0.0f;
    const int mBase = wave << 6;   // 64 gaussians per wave

    #pragma unroll 4
    for (int m = 0; m < 64; ++m) {
        const float4* w4 = reinterpret_cast<const float4*>(smemW + ((mBase + m) << 4));
        const float4 wa = w4[0];
        const float4 wb = w4[1];
        const float4 wc = w4[2];
        const float4 wd = w4[3];

        v2f cA = mkv2(wa.x, wa.y) * f0;
        v2f cB = mkv2(wa.z, wa.w) * f1;
        cA = fma2(mkv2(wb.x, wb.y), f2, cA);
        cB = fma2(mkv2(wb.z, wb.w), f3, cB);
        cA = fma2(mkv2(wc.x, wc.y), f4, cA);
        cB = fma2(mkv2(wc.z, wc.w), f5, cB);
        cA = fma2(mkv2(wd.x, wd.y), f6, cA);
        cA = cA + cB;
        const float s = (cA.x + cA.y) + wd.z;
        acc = fmaf(wd.w, fexp2(s), acc);
    }

    // ---------------- Phase 3: cross-wave reduction + sigmoid ---------------
    __syncthreads();                 // W table dead; reuse as reduction scratch
    smemW[(wave << 6) + lane] = acc;
    __syncthreads();

    if (wave == 0) {
        float t = 0.0f;
        #pragma unroll
        for (int w = 0; w < 16; ++w) t += smemW[(w << 6) + lane];
        const float e = fexp2(-t * 1.4426950408889634f);
        out[ray] = 1.0f / (1.0f + e);
    }
}

extern "C" void kernel_launch(void* const* d_in, const int* in_sizes, int n_in,
                              void* d_out, int out_size, void* d_ws, size_t ws_size,
                              hipStream_t stream) {
    const float* origins    = (const float*)d_in[0];  // [N,2]
    const float* directions = (const float*)d_in[1];  // [N,2]
    const float* means      = (const float*)d_in[2];  // [M,4]
    const float* covs       = (const float*)d_in[3];  // [M,4,4]
    const float* labels     = (const float*)d_in[4];  // [M]
    float* out = (float*)d_out;

    decoder_fused<<<dim3(N_RAYS / 64), dim3(1024), 0, stream>>>(
        (const float2*)origins, (const float2*)directions, means, covs, labels, out);
}

// Round 3
// 78.045 us; speedup vs baseline: 1.2873x; 1.0348x over previous
//
#include <hip/hip_runtime.h>
#include <math.h>

#define M_GAUSS 1024
#define N_RAYS  32768

typedef float v2f __attribute__((ext_vector_type(2)));

__device__ __forceinline__ float fexp2(float x) {
#if __has_builtin(__builtin_amdgcn_exp2f)
    return __builtin_amdgcn_exp2f(x);
#else
    return exp2f(x);
#endif
}

__device__ __forceinline__ v2f fma2(v2f a, v2f b, v2f c) {
#if __has_builtin(__builtin_elementwise_fma)
    return __builtin_elementwise_fma(a, b, c);
#else
    v2f r; r.x = fmaf(a.x, b.x, c.x); r.y = fmaf(a.y, b.y, c.y); return r;
#endif
}

__device__ __forceinline__ v2f mkv2(float x, float y) { v2f r; r.x = x; r.y = y; return r; }

// ---------------------------------------------------------------------------
// Prep: invert each 4x4 SPD covariance (fp32 adjugate; det >= 1 so well
// conditioned) and pack 16 coeffs per gaussian into global W so the hot loop
// is a 15-term dot product with k = -0.5*log2(e) folded in:
//   pdf = label * exp2( dot(w[0..13], features) + w[14] )
// ---------------------------------------------------------------------------
__global__ __launch_bounds__(256) void prep_kernel(
    const float* __restrict__ means,   // [M,4]
    const float* __restrict__ covs,    // [M,4,4]
    const float* __restrict__ labels,  // [M]
    float* __restrict__ W)             // [M,16]
{
    const int g = blockIdx.x * blockDim.x + threadIdx.x;
    if (g >= M_GAUSS) return;

    const float4* C4 = reinterpret_cast<const float4*>(covs + 16 * g);
    const float4 r0 = C4[0], r1 = C4[1], r2 = C4[2], r3 = C4[3];
    const float a00=r0.x, a01=r0.y, a02=r0.z, a03=r0.w;
    const float a10=r1.x, a11=r1.y, a12=r1.z, a13=r1.w;
    const float a20=r2.x, a21=r2.y, a22=r2.z, a23=r2.w;
    const float a30=r3.x, a31=r3.y, a32=r3.z, a33=r3.w;

    const float s0=a00*a11-a01*a10, s1=a00*a12-a02*a10, s2=a00*a13-a03*a10;
    const float s3=a01*a12-a02*a11, s4=a01*a13-a03*a11, s5=a02*a13-a03*a12;
    const float c5=a22*a33-a23*a32, c4=a21*a33-a23*a31, c3=a21*a32-a22*a31;
    const float c2=a20*a33-a23*a30, c1=a20*a32-a22*a30, c0=a20*a31-a21*a30;
    const float det = s0*c5 - s1*c4 + s2*c3 + s3*c2 - s4*c1 + s5*c0;
    const float id  = 1.0f / det;

    const float b00=( a11*c5 - a12*c4 + a13*c3)*id;
    const float b01=(-a01*c5 + a02*c4 - a03*c3)*id;
    const float b10=(-a10*c5 + a12*c2 - a13*c1)*id;
    const float b11=( a00*c5 - a02*c2 + a03*c1)*id;
    const float b20=( a10*c4 - a11*c2 + a13*c0)*id;
    const float b21=(-a00*c4 + a01*c2 - a03*c0)*id;
    const float b30=(-a10*c3 + a11*c1 - a12*c0)*id;
    const float b31=( a00*c3 - a01*c1 + a02*c0)*id;
    const float b02=( a31*s5 - a32*s4 + a33*s3)*id;
    const float b03=(-a21*s5 + a22*s4 - a23*s3)*id;
    const float b12=(-a30*s5 + a32*s2 - a33*s1)*id;
    const float b13=( a20*s5 - a22*s2 + a23*s1)*id;
    const float b22=( a30*s4 - a31*s2 + a33*s0)*id;
    const float b23=(-a20*s4 + a21*s2 - a23*s0)*id;
    const float b32=(-a30*s3 + a31*s1 - a32*s0)*id;
    const float b33=( a20*s3 - a21*s1 + a22*s0)*id;

    const float m01=0.5f*(b01+b10), m02=0.5f*(b02+b20), m03=0.5f*(b03+b30);
    const float m12=0.5f*(b12+b21), m13=0.5f*(b13+b31), m23=0.5f*(b23+b32);

    const float4 mu = reinterpret_cast<const float4*>(means)[g];
    const float u0=mu.x, u1=mu.y, u2=mu.z, u3=mu.w;
    const float v0 = b00*u0 + m01*u1 + m02*u2 + m03*u3;
    const float v1 = m01*u0 + b11*u1 + m12*u2 + m13*u3;
    const float v2 = m02*u0 + m12*u1 + b22*u2 + m23*u3;
    const float v3 = m03*u0 + m13*u1 + m23*u2 + b33*u3;
    const float cc = u0*v0 + u1*v1 + u2*v2 + u3*v3;

    const float k  = -0.72134752044448170368f;   // -0.5 * log2(e)
    const float k2 = 2.0f * k;
    float4* w4 = reinterpret_cast<float4*>(W + 16 * g);
    w4[0] = make_float4(k*b00,  k*b11,  k*b22,  k*b33);
    w4[1] = make_float4(k2*m01, k2*m02, k2*m03, k2*m12);
    w4[2] = make_float4(k2*m13, k2*m23, -k2*v0, -k2*v1);
    w4[3] = make_float4(-k2*v2, -k2*v3, k*cc,   labels[g]);
}

// ---------------------------------------------------------------------------
// Main: block = 1024 threads = 16 waves, 64 rays/block (lane = ray), wave w
// sweeps gaussians [64w, 64w+64). The gaussian pointer is made wave-uniform
// with readfirstlane so coefficient loads compile to s_load_dwordx16 on the
// scalar pipe — no LDS traffic, 64 B fetched ONCE per wave (vs 1 KB of LDS
// return-path per ds_read_b128 broadcast in the previous version). 32
// waves/CU (tiny LDS, ~20 VGPRs) hide the K$/L2 scalar-load latency.
// ---------------------------------------------------------------------------
__global__ __launch_bounds__(1024, 8) void decoder_kernel(
    const float2* __restrict__ org,   // [N]
    const float2* __restrict__ dir,   // [N]
    const float*  __restrict__ W,     // [M,16]
    float*        __restrict__ out)   // [N]
{
    const int tid  = threadIdx.x;
    const int lane = tid & 63;
    const int wave = tid >> 6;
    const int ray  = (blockIdx.x << 6) + lane;

    const float2 o = org[ray];
    const float2 d = dir[ray];
    const float p0=o.x, p1=o.y, p2=d.x, p3=d.y;

    const v2f f0 = mkv2(p0*p0, p1*p1);
    const v2f f1 = mkv2(p2*p2, p3*p3);
    const v2f f2 = mkv2(p0*p1, p0*p2);
    const v2f f3 = mkv2(p0*p3, p1*p2);
    const v2f f4 = mkv2(p1*p3, p2*p3);
    const v2f f5 = mkv2(p0, p1);
    const v2f f6 = mkv2(p2, p3);

    // wave-uniform base pointer -> scalar loads
    const float* wptr = W + (__builtin_amdgcn_readfirstlane(wave << 6) << 4);

    float acc = 0.0f;
    #pragma unroll 4
    for (int m = 0; m < 64; ++m) {
        const float4* w4 = reinterpret_cast<const float4*>(wptr + (m << 4));
        const float4 wa = w4[0];
        const float4 wb = w4[1];
        const float4 wc = w4[2];
        const float4 wd = w4[3];

        v2f cA = mkv2(wa.x, wa.y) * f0;
        v2f cB = mkv2(wa.z, wa.w) * f1;
        cA = fma2(mkv2(wb.x, wb.y), f2, cA);
        cB = fma2(mkv2(wb.z, wb.w), f3, cB);
        cA = fma2(mkv2(wc.x, wc.y), f4, cA);
        cB = fma2(mkv2(wc.z, wc.w), f5, cB);
        cA = fma2(mkv2(wd.x, wd.y), f6, cA);
        cA = cA + cB;
        acc = fmaf(wd.w, fexp2(cA.x + cA.y + wd.z), acc);
    }

    __shared__ float partial[16][64];
    partial[wave][lane] = acc;
    __syncthreads();

    if (wave == 0) {
        float t = 0.0f;
        #pragma unroll
        for (int w = 0; w < 16; ++w) t += partial[w][lane];   // 2-way bank alias: free
        const float e = fexp2(-t * 1.4426950408889634f);
        out[ray] = 1.0f / (1.0f + e);
    }
}

extern "C" void kernel_launch(void* const* d_in, const int* in_sizes, int n_in,
                              void* d_out, int out_size, void* d_ws, size_t ws_size,
                              hipStream_t stream) {
    const float* origins    = (const float*)d_in[0];  // [N,2]
    const float* directions = (const float*)d_in[1];  // [N,2]
    const float* means      = (const float*)d_in[2];  // [M,4]
    const float* covs       = (const float*)d_in[3];  // [M,4,4]
    const float* labels     = (const float*)d_in[4];  // [M]
    float* out = (float*)d_out;
    float* W   = (float*)d_ws;                        // [M,16] = 64 KB

    prep_kernel<<<dim3(M_GAUSS / 256), dim3(256), 0, stream>>>(means, covs, labels, W);
    decoder_kernel<<<dim3(N_RAYS / 64), dim3(1024), 0, stream>>>(
        (const float2*)origins, (const float2*)directions, W, out);
}